// Round 7
// baseline (696.849 us; speedup 1.0000x reference)
//
#include <hip/hip_runtime.h>

#define Bn 512
#define Tn 512
#define Dn 64
#define Hn 128
#define Ln 32

typedef __attribute__((ext_vector_type(8))) short short8v;
typedef __attribute__((ext_vector_type(4))) float float4v;
typedef __attribute__((ext_vector_type(2))) float float2v;

__device__ __forceinline__ unsigned short f2bf(float f){
  unsigned int u = __float_as_uint(f);
  u += 0x7FFFu + ((u >> 16) & 1u);           // round-to-nearest-even
  return (unsigned short)(u >> 16);
}

__device__ __forceinline__ short8v pack8(float4v a, float4v b){
  short8v r;
  r[0]=(short)f2bf(a[0]); r[1]=(short)f2bf(a[1]);
  r[2]=(short)f2bf(a[2]); r[3]=(short)f2bf(a[3]);
  r[4]=(short)f2bf(b[0]); r[5]=(short)f2bf(b[1]);
  r[6]=(short)f2bf(b[2]); r[7]=(short)f2bf(b[3]);
  return r;
}

// B-fragment for mfma_f32_16x16x32_bf16: lane holds W[n=base+(lane&15)][k0 + 8*(lane>>4) + i]
__device__ __forceinline__ short8v load_wfrag(const float* __restrict__ W, int n, int k0, int ldk){
  const float* p = W + (size_t)n*(size_t)ldk + (size_t)k0;
  float4v a = *(const float4v*)p;
  float4v b = *(const float4v*)(p+4);
  return pack8(a,b);
}

__device__ __forceinline__ float4v mfma16(short8v a, short8v b, float4v c){
  return __builtin_amdgcn_mfma_f32_16x16x32_bf16(a, b, c, 0, 0, 0);
}

__device__ __forceinline__ float sigm(float v){
  return __builtin_amdgcn_rcpf(1.0f + __expf(-v));
}
__device__ __forceinline__ float tanh_(float v){
  return 1.0f - 2.0f*__builtin_amdgcn_rcpf(1.0f + __expf(2.0f*v));
}

// Raw barrier: lgkmcnt-only drain (no vmcnt) so global loads/stores stay in flight.
__device__ __forceinline__ void bar_lds(){
  __builtin_amdgcn_sched_barrier(0);
  asm volatile("s_waitcnt lgkmcnt(0)" ::: "memory");
  __builtin_amdgcn_s_barrier();
  __builtin_amdgcn_sched_barrier(0);
}

// ---------------- precompute: W_eff = dW_hh + dW_ih @ oW ; b_eff = bd + dW_ih @ ob ----------------
__global__ __launch_bounds__(256) void weff_kernel(
    const float* __restrict__ dW_ih, const float* __restrict__ dW_hh,
    const float* __restrict__ db_ih, const float* __restrict__ db_hh,
    const float* __restrict__ oW,    const float* __restrict__ ob,
    float* __restrict__ ws)
{
  int id = blockIdx.x*256 + threadIdx.x;
  if (id < 512*128) {
    int n = id >> 7, h = id & 127;
    float s = dW_hh[id];
    #pragma unroll 8
    for (int d = 0; d < Dn; ++d) s += dW_ih[n*Dn + d] * oW[d*Hn + h];
    ws[id] = s;
  } else if (id < 512*128 + 512) {
    int n = id - 512*128;
    float s = db_ih[n] + db_hh[n];
    #pragma unroll 8
    for (int d = 0; d < Dn; ++d) s += dW_ih[n*Dn + d] * ob[d];
    ws[512*128 + n] = s;
  }
}

// ---------------- main fused kernel: 8 waves, 2 rows/block ----------------
__global__ __launch_bounds__(512, 2) void vae_fused(
    const float* __restrict__ x,     const float* __restrict__ eps,
    const float* __restrict__ eW_ih, const float* __restrict__ eW_hh,
    const float* __restrict__ eb_ih, const float* __restrict__ eb_hh,
    const float* __restrict__ muW,   const float* __restrict__ mub,
    const float* __restrict__ lvW,   const float* __restrict__ lvb,
    const float* __restrict__ iW,    const float* __restrict__ ib,
    const float* __restrict__ dW_hh, const float* __restrict__ db_ih,
    const float* __restrict__ db_hh, const float* __restrict__ oW,
    const float* __restrict__ ob,    const float* __restrict__ ws,
    float* __restrict__ out)
{
  __shared__ __align__(16) float gxb[8*4*128*2];          // 32 KB: gx for 8 steps [t][gate][col][r]
  __shared__ __align__(16) unsigned short h_lds[2*2*128]; // 1 KB: double-buffered h, 2 rows each
  __shared__ __align__(16) float sc_h[2*Hn];
  __shared__ __align__(16) float sc_mu[2*Ln];
  __shared__ __align__(16) float sc_lv[2*Ln];
  __shared__ __align__(16) float sc_z[2*Ln];

  const int tid  = threadIdx.x;
  const int lane = tid & 63;
  const int w    = tid >> 6;           // wave 0..7: owns h-indices [w*16, w*16+16)
  const int m    = lane & 15;          // fragment col (C) / A row
  const int q    = lane >> 4;          // k-group
  const int hrow = m & 1;              // replicated batch row for h/A reads
  const int jown = w*16 + m;           // h-index this lane owns
  const int b0   = blockIdx.x * 2;
  // per-lane LDS pointers
  char* const hwq_p = (char*)h_lds + q*256 + ((2*jown) ^ (q<<4));          // h write (q<2)
  const char* const hr_p = (const char*)h_lds + hrow*256 + ((q*16) ^ (hrow<<4)); // h-frag read
  const char* const gx_p = (const char*)gxb + jown*8;                      // gx read base
  char* const gw_p = (char*)gxb + jown*8 + q*8192;                         // gx write base

  // ---- zero h buffers ----
  if (tid < 256) ((int*)h_lds)[tid] = 0;

  // ---- encoder weights: tile nt (=gate) -> row n = nt*128 + jown ----
  short8v wih[8];    // [nt*2+kt] : 4H x D
  short8v whh[16];   // [nt*4+kt] : 4H x H
  #pragma unroll
  for (int nt = 0; nt < 4; ++nt) {
    #pragma unroll
    for (int kt = 0; kt < 2; ++kt) wih[nt*2+kt] = load_wfrag(eW_ih, nt*128 + jown, kt*32 + q*8, Dn);
    #pragma unroll
    for (int kt = 0; kt < 4; ++kt) whh[nt*4+kt] = load_wfrag(eW_hh, nt*128 + jown, kt*32 + q*8, Hn);
  }
  float bia[4];
  #pragma unroll
  for (int g = 0; g < 4; ++g) bia[g] = eb_ih[g*128 + jown] + eb_hh[g*128 + jown];

  // ---- x batch registers: lane (m,q) holds x[b0+(m&1)][tb*8 + (m>>1)][kt*32+q*8 ..+8] ----
  const float* xbase = x + (size_t)(b0 + hrow)*Tn*Dn + (size_t)(m>>1)*Dn + q*8;
  float4v xc0,xc1,xc2,xc3, xn0,xn1,xn2,xn3;
  xc0 = *(const float4v*)(xbase+0);  xc1 = *(const float4v*)(xbase+4);
  xc2 = *(const float4v*)(xbase+32); xc3 = *(const float4v*)(xbase+36);

  float cst0 = 0.f, cst1 = 0.f, h0 = 0.f, h1 = 0.f;
  __syncthreads();

#define RH(RB,KB)  (*(const short8v*)(hr_p + (RB)*512 + (KB)))
#define RGX(S,NT)  (*(const float2v*)(gx_p + (S)*4096 + (NT)*1024))

  // gx batch: one M=16 MFMA block computes x@Wih^T(+bias) for 8 steps x 2 rows (all rows real).
  // C row q*4+j -> (t = 2q+(j>>1), r = j&1); write addr = t*4096 + nt*1024 + jown*8 + r*4.
#define BATCH(TB) do { \
    short8v xf0 = pack8(xc0, xc1); \
    short8v xf1 = pack8(xc2, xc3); \
    if ((TB) < 63) { \
      const float* xp = xbase + ((TB)+1)*512; \
      xn0 = *(const float4v*)(xp+0);  xn1 = *(const float4v*)(xp+4); \
      xn2 = *(const float4v*)(xp+32); xn3 = *(const float4v*)(xp+36); \
    } \
    float4v zz = {0.f,0.f,0.f,0.f}; \
    float4v c0_ = mfma16(xf0, wih[0], zz); \
    float4v c1_ = mfma16(xf0, wih[2], zz); \
    float4v c2_ = mfma16(xf0, wih[4], zz); \
    float4v c3_ = mfma16(xf0, wih[6], zz); \
    c0_ = mfma16(xf1, wih[1], c0_); \
    c1_ = mfma16(xf1, wih[3], c1_); \
    c2_ = mfma16(xf1, wih[5], c2_); \
    c3_ = mfma16(xf1, wih[7], c3_); \
    *(float2v*)(gw_p +        0) = (float2v){c0_[0]+bia[0], c0_[1]+bia[0]}; \
    *(float2v*)(gw_p +     1024) = (float2v){c1_[0]+bia[1], c1_[1]+bia[1]}; \
    *(float2v*)(gw_p +     2048) = (float2v){c2_[0]+bia[2], c2_[1]+bia[2]}; \
    *(float2v*)(gw_p +     3072) = (float2v){c3_[0]+bia[3], c3_[1]+bia[3]}; \
    *(float2v*)(gw_p + 4096 + 0)    = (float2v){c0_[2]+bia[0], c0_[3]+bia[0]}; \
    *(float2v*)(gw_p + 4096 + 1024) = (float2v){c1_[2]+bia[1], c1_[3]+bia[1]}; \
    *(float2v*)(gw_p + 4096 + 2048) = (float2v){c2_[2]+bia[2], c2_[3]+bia[2]}; \
    *(float2v*)(gw_p + 4096 + 3072) = (float2v){c3_[2]+bia[3], c3_[3]+bia[3]}; \
    xc0=xn0; xc1=xn1; xc2=xn2; xc3=xn3; \
    bar_lds(); \
  } while(0)

  // nonlin: reg0 = batch row 0, reg1 = row 1 for EVERY lane (static indices, both chains per lane)
#define NONLIN2(GI0,GI1,GF0,GF1,GG0,GG1,GO0,GO1, WB) do { \
    float nc0 = sigm(GF0)*cst0 + sigm(GI0)*tanh_(GG0); \
    float nc1 = sigm(GF1)*cst1 + sigm(GI1)*tanh_(GG1); \
    cst0 = nc0; cst1 = nc1; \
    h0 = sigm(GO0)*tanh_(nc0); h1 = sigm(GO1)*tanh_(nc1); \
    if (q < 2) *(unsigned short*)(hwq_p + (WB)*512) = f2bf(q ? h1 : h0); \
  } while(0)

#define HH16(RB) \
    short8v hf0 = RH(RB,0), hf1 = RH(RB,64), hf2 = RH(RB,128), hf3 = RH(RB,192); \
    float4v zz = {0.f,0.f,0.f,0.f}; \
    float4v a0 = mfma16(hf0, whh[0],  zz); \
    float4v a1 = mfma16(hf0, whh[4],  zz); \
    float4v a2 = mfma16(hf0, whh[8],  zz); \
    float4v a3 = mfma16(hf0, whh[12], zz); \
    a0 = mfma16(hf1, whh[1],  a0); a1 = mfma16(hf1, whh[5],  a1); \
    a2 = mfma16(hf1, whh[9],  a2); a3 = mfma16(hf1, whh[13], a3); \
    a0 = mfma16(hf2, whh[2],  a0); a1 = mfma16(hf2, whh[6],  a1); \
    a2 = mfma16(hf2, whh[10], a2); a3 = mfma16(hf2, whh[14], a3); \
    a0 = mfma16(hf3, whh[3],  a0); a1 = mfma16(hf3, whh[7],  a1); \
    a2 = mfma16(hf3, whh[11], a2); a3 = mfma16(hf3, whh[15], a3);

#define ENC_STEP(S, RB) do { \
    float2v g0 = RGX(S,0), g1 = RGX(S,1), g2 = RGX(S,2), g3 = RGX(S,3); \
    HH16(RB); \
    NONLIN2(a0[0]+g0[0], a0[1]+g0[1], a1[0]+g1[0], a1[1]+g1[1], \
            a2[0]+g2[0], a2[1]+g2[1], a3[0]+g3[0], a3[1]+g3[1], (RB)^1); \
    bar_lds(); \
  } while(0)

  // ================= encoder: 64 batches x 8 steps =================
  #pragma unroll 1
  for (int tb = 0; tb < 64; ++tb) {
    BATCH(tb);
    ENC_STEP(0,0); ENC_STEP(1,1); ENC_STEP(2,0); ENC_STEP(3,1);
    ENC_STEP(4,0); ENC_STEP(5,1); ENC_STEP(6,0); ENC_STEP(7,1);
  }
  // final h in buffer 0; exact f32 copies in h0,h1 (all lanes)

  // ================= latent =================
  if (q == 0) { sc_h[jown] = h0; sc_h[Hn + jown] = h1; }
  __syncthreads();

  if (tid < 128) {
    const int isLv = tid >> 6;
    const int rr   = (tid >> 5) & 1;
    const int l    = tid & 31;
    const float* Wp = isLv ? lvW : muW;
    float s = isLv ? lvb[l] : mub[l];
    #pragma unroll
    for (int k = 0; k < Hn; k += 4) {
      float4v wv = *(const float4v*)(Wp + l*Hn + k);
      float4v hv = *(const float4v*)(sc_h + rr*Hn + k);
      s += wv[0]*hv[0] + wv[1]*hv[1] + wv[2]*hv[2] + wv[3]*hv[3];
    }
    out[(size_t)Bn*Tn*Dn + (size_t)isLv*Bn*Ln + (size_t)(b0+rr)*Ln + l] = s;
    (isLv ? sc_lv : sc_mu)[rr*Ln + l] = s;
  }
  __syncthreads();

  if (tid < 64) {
    int rr = tid >> 5, l = tid & 31;
    sc_z[rr*Ln+l] = sc_mu[rr*Ln+l] + eps[(size_t)(b0+rr)*Ln + l] * __expf(0.5f * sc_lv[rr*Ln+l]);
  }
  __syncthreads();

  if (tid < 256) { // decoder hidden init -> h buffer 0
    int rr = tid >> 7, jj = tid & 127;
    float s = ib[jj];
    #pragma unroll
    for (int l = 0; l < Ln; ++l) s += sc_z[rr*Ln + l] * iW[jj*Ln + l];
    *(unsigned short*)((char*)h_lds + rr*256 + ((2*jj) ^ (rr<<4))) = f2bf(s);
  }
  cst0 = 0.f; cst1 = 0.f;

  // ---- decoder step-0 weights (dW_hh, bd) + output-proj fragments ----
  #pragma unroll
  for (int nt = 0; nt < 4; ++nt)
    #pragma unroll
    for (int kt = 0; kt < 4; ++kt) whh[nt*4+kt] = load_wfrag(dW_hh, nt*128 + jown, kt*32 + q*8, Hn);
  #pragma unroll
  for (int g = 0; g < 4; ++g) bia[g] = db_ih[g*128 + jown] + db_hh[g*128 + jown];
  const int ocol = (w & 3)*16 + m;
  short8v ow0 = load_wfrag(oW, ocol,  0 + q*8, Hn);
  short8v ow1 = load_wfrag(oW, ocol, 32 + q*8, Hn);
  short8v ow2 = load_wfrag(oW, ocol, 64 + q*8, Hn);
  short8v ow3 = load_wfrag(oW, ocol, 96 + q*8, Hn);
  const float obv = ob[ocol];
  __syncthreads();

  // ---- decoder step 0: gates = h0 @ dW_hh^T + bd (input is zero) ----
  {
    HH16(0);
    NONLIN2(a0[0]+bia[0], a0[1]+bia[0], a1[0]+bia[1], a1[1]+bia[1],
            a2[0]+bia[2], a2[1]+bia[2], a3[0]+bia[3], a3[1]+bia[3], 1);
    bar_lds();
  }

  // ---- switch to folded weights: W_eff = dW_hh + dW_ih@oW ; b_eff ----
  {
    const float* weff = ws;
    const float* beff = ws + 512*128;
    #pragma unroll
    for (int nt = 0; nt < 4; ++nt)
      #pragma unroll
      for (int kt = 0; kt < 4; ++kt) whh[nt*4+kt] = load_wfrag(weff, nt*128 + jown, kt*32 + q*8, Hn);
    #pragma unroll
    for (int g = 0; g < 4; ++g) bia[g] = beff[g*128 + jown];
  }

  float* outp0 = out + (size_t)(b0+0)*Tn*Dn;
  float* outp1 = out + (size_t)(b0+1)*Tn*Dn;

#define DEC_STEP(RB) do { \
    HH16(RB); \
    if (w < 4) { \
      float4v ya = mfma16(hf0, ow0, zz); \
      ya = mfma16(hf1, ow1, ya); ya = mfma16(hf2, ow2, ya); ya = mfma16(hf3, ow3, ya); \
      if (q == 0) { outp0[ocol] = ya[0] + obv; outp1[ocol] = ya[1] + obv; } \
    } \
    outp0 += Dn; outp1 += Dn; \
    NONLIN2(a0[0]+bia[0], a0[1]+bia[0], a1[0]+bia[1], a1[1]+bia[1], \
            a2[0]+bia[2], a2[1]+bia[2], a3[0]+bia[3], a3[1]+bia[3], (RB)^1); \
    bar_lds(); \
  } while(0)

  // ---- decoder steps 1..511; y(i-1) computed from the same h(i) fragments ----
  #pragma unroll 1
  for (int i = 1; i < Tn-1; i += 2) {
    DEC_STEP(1);
    DEC_STEP(0);
  }
  DEC_STEP(1);

  // ---- epilogue: y(511) from h(512) (buffer 0) ----
  if (w < 4) {
    short8v hf0 = RH(0,0), hf1 = RH(0,64), hf2 = RH(0,128), hf3 = RH(0,192);
    float4v ya = {0.f,0.f,0.f,0.f};
    ya = mfma16(hf0, ow0, ya); ya = mfma16(hf1, ow1, ya);
    ya = mfma16(hf2, ow2, ya); ya = mfma16(hf3, ow3, ya);
    if (q == 0) {
      outp0[ocol] = ya[0] + obv;
      outp1[ocol] = ya[1] + obv;
    }
  }
#undef DEC_STEP
#undef ENC_STEP
#undef HH16
#undef NONLIN2
#undef BATCH
#undef RGX
#undef RH
}

extern "C" void kernel_launch(void* const* d_in, const int* in_sizes, int n_in,
                              void* d_out, int out_size, void* d_ws, size_t ws_size,
                              hipStream_t stream) {
  (void)in_sizes; (void)n_in; (void)ws_size; (void)out_size;
  const float* x     = (const float*)d_in[0];
  const float* eps   = (const float*)d_in[1];
  const float* eW_ih = (const float*)d_in[2];
  const float* eW_hh = (const float*)d_in[3];
  const float* eb_ih = (const float*)d_in[4];
  const float* eb_hh = (const float*)d_in[5];
  const float* muW   = (const float*)d_in[6];
  const float* mub   = (const float*)d_in[7];
  const float* lvW   = (const float*)d_in[8];
  const float* lvb   = (const float*)d_in[9];
  const float* iW    = (const float*)d_in[10];
  const float* ib    = (const float*)d_in[11];
  const float* dW_ih = (const float*)d_in[12];
  const float* dW_hh = (const float*)d_in[13];
  const float* db_ih = (const float*)d_in[14];
  const float* db_hh = (const float*)d_in[15];
  const float* oW    = (const float*)d_in[16];
  const float* ob    = (const float*)d_in[17];
  float* out = (float*)d_out;
  float* ws  = (float*)d_ws;

  weff_kernel<<<dim3(258), dim3(256), 0, stream>>>(dW_ih, dW_hh, db_ih, db_hh, oW, ob, ws);
  vae_fused<<<dim3(256), dim3(512), 0, stream>>>(
      x, eps, eW_ih, eW_hh, eb_ih, eb_hh, muW, mub, lvW, lvb,
      iW, ib, dW_hh, db_ih, db_hh, oW, ob, ws, out);
}

// Round 9
// 581.314 us; speedup vs baseline: 1.1987x; 1.1987x over previous
//
#include <hip/hip_runtime.h>

#define Bn 512
#define Tn 512
#define Dn 64
#define Hn 128
#define Ln 32
#define GXT 4128   // gx t-stride in bytes (4096 + 32 bank-shift to kill write conflicts)

typedef __attribute__((ext_vector_type(8))) short short8v;
typedef __attribute__((ext_vector_type(4))) float float4v;
typedef __attribute__((ext_vector_type(2))) float float2v;

__device__ __forceinline__ unsigned short f2bf(float f){
  unsigned int u = __float_as_uint(f);
  u += 0x7FFFu + ((u >> 16) & 1u);           // round-to-nearest-even
  return (unsigned short)(u >> 16);
}

__device__ __forceinline__ short8v pack8(float4v a, float4v b){
  short8v r;
  r[0]=(short)f2bf(a[0]); r[1]=(short)f2bf(a[1]);
  r[2]=(short)f2bf(a[2]); r[3]=(short)f2bf(a[3]);
  r[4]=(short)f2bf(b[0]); r[5]=(short)f2bf(b[1]);
  r[6]=(short)f2bf(b[2]); r[7]=(short)f2bf(b[3]);
  return r;
}

// B-fragment for mfma_f32_16x16x32_bf16: lane holds W[n=base+(lane&15)][k0 + 8*(lane>>4) + i]
__device__ __forceinline__ short8v load_wfrag(const float* __restrict__ W, int n, int k0, int ldk){
  const float* p = W + (size_t)n*(size_t)ldk + (size_t)k0;
  float4v a = *(const float4v*)p;
  float4v b = *(const float4v*)(p+4);
  return pack8(a,b);
}

__device__ __forceinline__ float4v mfma16(short8v a, short8v b, float4v c){
  return __builtin_amdgcn_mfma_f32_16x16x32_bf16(a, b, c, 0, 0, 0);
}

__device__ __forceinline__ float sigm(float v){
  return __builtin_amdgcn_rcpf(1.0f + __expf(-v));
}
__device__ __forceinline__ float tanh_(float v){
  return 1.0f - 2.0f*__builtin_amdgcn_rcpf(1.0f + __expf(2.0f*v));
}

// Raw barrier: lgkmcnt-only drain (no vmcnt) so global loads/stores stay in flight.
__device__ __forceinline__ void bar_lds(){
  __builtin_amdgcn_sched_barrier(0);
  asm volatile("s_waitcnt lgkmcnt(0)" ::: "memory");
  __builtin_amdgcn_s_barrier();
  __builtin_amdgcn_sched_barrier(0);
}

// ---------------- precompute: W_eff = dW_hh + dW_ih @ oW ; b_eff = bd + dW_ih @ ob ----------------
__global__ __launch_bounds__(256) void weff_kernel(
    const float* __restrict__ dW_ih, const float* __restrict__ dW_hh,
    const float* __restrict__ db_ih, const float* __restrict__ db_hh,
    const float* __restrict__ oW,    const float* __restrict__ ob,
    float* __restrict__ ws)
{
  int id = blockIdx.x*256 + threadIdx.x;
  if (id < 512*128) {
    int n = id >> 7, h = id & 127;
    float s = dW_hh[id];
    #pragma unroll 8
    for (int d = 0; d < Dn; ++d) s += dW_ih[n*Dn + d] * oW[d*Hn + h];
    ws[id] = s;
  } else if (id < 512*128 + 512) {
    int n = id - 512*128;
    float s = db_ih[n] + db_hh[n];
    #pragma unroll 8
    for (int d = 0; d < Dn; ++d) s += dW_ih[n*Dn + d] * ob[d];
    ws[512*128 + n] = s;
  }
}

// ---------------- main fused kernel: 8 waves, 2 rows/block ----------------
__global__ __launch_bounds__(512, 2) void vae_fused(
    const float* __restrict__ x,     const float* __restrict__ eps,
    const float* __restrict__ eW_ih, const float* __restrict__ eW_hh,
    const float* __restrict__ eb_ih, const float* __restrict__ eb_hh,
    const float* __restrict__ muW,   const float* __restrict__ mub,
    const float* __restrict__ lvW,   const float* __restrict__ lvb,
    const float* __restrict__ iW,    const float* __restrict__ ib,
    const float* __restrict__ dW_hh, const float* __restrict__ db_ih,
    const float* __restrict__ db_hh, const float* __restrict__ oW,
    const float* __restrict__ ob,    const float* __restrict__ ws,
    float* __restrict__ out)
{
  __shared__ __align__(16) char gxb[8*GXT];               // ~33 KB: gx for 8 steps [t][gate][col][r]
  __shared__ __align__(16) unsigned short h_lds[2*2*128]; // 1 KB: double-buffered h, 2 rows each
  __shared__ __align__(16) float sc_h[2*Hn];
  __shared__ __align__(16) float sc_mu[2*Ln];
  __shared__ __align__(16) float sc_lv[2*Ln];
  __shared__ __align__(16) float sc_z[2*Ln];

  const int tid  = threadIdx.x;
  const int lane = tid & 63;
  const int w    = tid >> 6;           // wave 0..7: owns h-indices [w*16, w*16+16)
  const int m    = lane & 15;          // fragment col (C) / A row
  const int q    = lane >> 4;          // k-group; r = q&1 selects this lane's batch row
  const int hrow = m & 1;              // replicated batch row for h/A reads
  const int rsel = q & 1;              // batch row this lane's nonlin chain owns
  const int jown = w*16 + m;           // h-index this lane owns
  const int b0   = blockIdx.x * 2;
  // per-lane LDS pointers
  char* const hwq_p = (char*)h_lds + q*256 + ((2*jown) ^ (q<<4));          // h write (q<2)
  const char* const hr_p = (const char*)h_lds + hrow*256 + ((q*16) ^ (hrow<<4)); // h-frag read
  const char* const gx_p = gxb + jown*8;                                   // gx read base
  char* const gw_p = gxb + jown*8 + q*(2*GXT);                             // gx write base (t=2q)

  // ---- zero h buffers ----
  if (tid < 256) ((int*)h_lds)[tid] = 0;

  // ---- encoder weights: tile nt (=gate) -> row n = nt*128 + jown ----
  short8v wih[8];    // [nt*2+kt] : 4H x D
  short8v whh[16];   // [nt*4+kt] : 4H x H
  #pragma unroll
  for (int nt = 0; nt < 4; ++nt) {
    #pragma unroll
    for (int kt = 0; kt < 2; ++kt) wih[nt*2+kt] = load_wfrag(eW_ih, nt*128 + jown, kt*32 + q*8, Dn);
    #pragma unroll
    for (int kt = 0; kt < 4; ++kt) whh[nt*4+kt] = load_wfrag(eW_hh, nt*128 + jown, kt*32 + q*8, Hn);
  }
  float bia[4];
  #pragma unroll
  for (int g = 0; g < 4; ++g) bia[g] = eb_ih[g*128 + jown] + eb_hh[g*128 + jown];

  // ---- x batch registers: lane (m,q) holds x[b0+(m&1)][tb*8 + (m>>1)][q*8 ..+8, +32..] ----
  const float* xbase = x + (size_t)(b0 + hrow)*Tn*Dn + (size_t)(m>>1)*Dn + q*8;
  float4v xc0,xc1,xc2,xc3, xn0,xn1,xn2,xn3;
  xc0 = *(const float4v*)(xbase+0);  xc1 = *(const float4v*)(xbase+4);
  xc2 = *(const float4v*)(xbase+32); xc3 = *(const float4v*)(xbase+36);

  float cst = 0.f, hval = 0.f;        // per-lane c/h for (rsel, jown)
  __syncthreads();

#define RH(RB,KB)  (*(const short8v*)(hr_p + (RB)*512 + (KB)))
#define RGX(S,NT)  (*(const float2v*)(gx_p + (S)*GXT + (NT)*1024))

  // gx batch: one M=16 MFMA block computes x@Wih^T(+bias) for 8 steps x 2 rows (all rows real).
  // C row q*4+j -> (t = 2q+(j>>1), r = j&1); write addr = t*GXT + nt*1024 + jown*8 + r*4.
#define BATCH(TB) do { \
    short8v xf0 = pack8(xc0, xc1); \
    short8v xf1 = pack8(xc2, xc3); \
    if ((TB) < 63) { \
      const float* xp = xbase + ((TB)+1)*512; \
      xn0 = *(const float4v*)(xp+0);  xn1 = *(const float4v*)(xp+4); \
      xn2 = *(const float4v*)(xp+32); xn3 = *(const float4v*)(xp+36); \
    } \
    float4v zz = {0.f,0.f,0.f,0.f}; \
    float4v c0_ = mfma16(xf0, wih[0], zz); \
    float4v c1_ = mfma16(xf0, wih[2], zz); \
    float4v c2_ = mfma16(xf0, wih[4], zz); \
    float4v c3_ = mfma16(xf0, wih[6], zz); \
    c0_ = mfma16(xf1, wih[1], c0_); \
    c1_ = mfma16(xf1, wih[3], c1_); \
    c2_ = mfma16(xf1, wih[5], c2_); \
    c3_ = mfma16(xf1, wih[7], c3_); \
    *(float2v*)(gw_p +       0) = (float2v){c0_[0]+bia[0], c0_[1]+bia[0]}; \
    *(float2v*)(gw_p +    1024) = (float2v){c1_[0]+bia[1], c1_[1]+bia[1]}; \
    *(float2v*)(gw_p +    2048) = (float2v){c2_[0]+bia[2], c2_[1]+bia[2]}; \
    *(float2v*)(gw_p +    3072) = (float2v){c3_[0]+bia[3], c3_[1]+bia[3]}; \
    *(float2v*)(gw_p + GXT +    0) = (float2v){c0_[2]+bia[0], c0_[3]+bia[0]}; \
    *(float2v*)(gw_p + GXT + 1024) = (float2v){c1_[2]+bia[1], c1_[3]+bia[1]}; \
    *(float2v*)(gw_p + GXT + 2048) = (float2v){c2_[2]+bia[2], c2_[3]+bia[2]}; \
    *(float2v*)(gw_p + GXT + 3072) = (float2v){c3_[2]+bia[3], c3_[3]+bia[3]}; \
    xc0=xn0; xc1=xn1; xc2=xn2; xc3=xn3; \
    bar_lds(); \
  } while(0)

  // ONE chain per lane (r = q&1); q=0/1 write rows 0/1, q=2/3 redundant SIMT copies.
#define NONLIN1(GI,GF,GG,GO, WB) do { \
    float c = sigm(GF)*cst + sigm(GI)*tanh_(GG); \
    cst = c; \
    hval = sigm(GO)*tanh_(c); \
    if (q < 2) *(unsigned short*)(hwq_p + (WB)*512) = f2bf(hval); \
  } while(0)

#define HH16(RB) \
    short8v hf0 = RH(RB,0), hf1 = RH(RB,64), hf2 = RH(RB,128), hf3 = RH(RB,192); \
    float4v zz = {0.f,0.f,0.f,0.f}; \
    float4v a0 = mfma16(hf0, whh[0],  zz); \
    float4v a1 = mfma16(hf0, whh[4],  zz); \
    float4v a2 = mfma16(hf0, whh[8],  zz); \
    float4v a3 = mfma16(hf0, whh[12], zz); \
    a0 = mfma16(hf1, whh[1],  a0); a1 = mfma16(hf1, whh[5],  a1); \
    a2 = mfma16(hf1, whh[9],  a2); a3 = mfma16(hf1, whh[13], a3); \
    a0 = mfma16(hf2, whh[2],  a0); a1 = mfma16(hf2, whh[6],  a1); \
    a2 = mfma16(hf2, whh[10], a2); a3 = mfma16(hf2, whh[14], a3); \
    a0 = mfma16(hf3, whh[3],  a0); a1 = mfma16(hf3, whh[7],  a1); \
    a2 = mfma16(hf3, whh[11], a2); a3 = mfma16(hf3, whh[15], a3);

#define ENC_STEP(S, RB) do { \
    float2v g0 = RGX(S,0), g1 = RGX(S,1), g2 = RGX(S,2), g3 = RGX(S,3); \
    HH16(RB); \
    float gi = rsel ? a0[1]+g0[1] : a0[0]+g0[0]; \
    float gf = rsel ? a1[1]+g1[1] : a1[0]+g1[0]; \
    float gg = rsel ? a2[1]+g2[1] : a2[0]+g2[0]; \
    float go = rsel ? a3[1]+g3[1] : a3[0]+g3[0]; \
    NONLIN1(gi, gf, gg, go, (RB)^1); \
    bar_lds(); \
  } while(0)

  // ================= encoder: 64 batches x 8 steps =================
  #pragma unroll 1
  for (int tb = 0; tb < 64; ++tb) {
    BATCH(tb);
    ENC_STEP(0,0); ENC_STEP(1,1); ENC_STEP(2,0); ENC_STEP(3,1);
    ENC_STEP(4,0); ENC_STEP(5,1); ENC_STEP(6,0); ENC_STEP(7,1);
  }
  // final h in buffer 0; exact f32 copy of owned element in hval (lanes q<2)

  // ================= latent =================
  if (q < 2) sc_h[q*Hn + jown] = hval;
  __syncthreads();

  if (tid < 128) {
    const int isLv = tid >> 6;
    const int rr   = (tid >> 5) & 1;
    const int l    = tid & 31;
    const float* Wp = isLv ? lvW : muW;
    float s = isLv ? lvb[l] : mub[l];
    #pragma unroll
    for (int k = 0; k < Hn; k += 4) {
      float4v wv = *(const float4v*)(Wp + l*Hn + k);
      float4v hv = *(const float4v*)(sc_h + rr*Hn + k);
      s += wv[0]*hv[0] + wv[1]*hv[1] + wv[2]*hv[2] + wv[3]*hv[3];
    }
    out[(size_t)Bn*Tn*Dn + (size_t)isLv*Bn*Ln + (size_t)(b0+rr)*Ln + l] = s;
    (isLv ? sc_lv : sc_mu)[rr*Ln + l] = s;
  }
  __syncthreads();

  if (tid < 64) {
    int rr = tid >> 5, l = tid & 31;
    sc_z[rr*Ln+l] = sc_mu[rr*Ln+l] + eps[(size_t)(b0+rr)*Ln + l] * __expf(0.5f * sc_lv[rr*Ln+l]);
  }
  __syncthreads();

  if (tid < 256) { // decoder hidden init -> h buffer 0
    int rr = tid >> 7, jj = tid & 127;
    float s = ib[jj];
    #pragma unroll
    for (int l = 0; l < Ln; ++l) s += sc_z[rr*Ln + l] * iW[jj*Ln + l];
    *(unsigned short*)((char*)h_lds + rr*256 + ((2*jj) ^ (rr<<4))) = f2bf(s);
  }
  cst = 0.f;

  // ---- decoder step-0 weights (dW_hh, bd) + output-proj fragments ----
  #pragma unroll
  for (int nt = 0; nt < 4; ++nt)
    #pragma unroll
    for (int kt = 0; kt < 4; ++kt) whh[nt*4+kt] = load_wfrag(dW_hh, nt*128 + jown, kt*32 + q*8, Hn);
  #pragma unroll
  for (int g = 0; g < 4; ++g) bia[g] = db_ih[g*128 + jown] + db_hh[g*128 + jown];
  const int ocol = (w & 3)*16 + m;
  short8v ow0 = load_wfrag(oW, ocol,  0 + q*8, Hn);
  short8v ow1 = load_wfrag(oW, ocol, 32 + q*8, Hn);
  short8v ow2 = load_wfrag(oW, ocol, 64 + q*8, Hn);
  short8v ow3 = load_wfrag(oW, ocol, 96 + q*8, Hn);
  const float obv = ob[ocol];
  __syncthreads();

  // ---- decoder step 0: gates = h0 @ dW_hh^T + bd (input is zero) ----
  {
    HH16(0);
    float gi = (rsel ? a0[1] : a0[0]) + bia[0];
    float gf = (rsel ? a1[1] : a1[0]) + bia[1];
    float gg = (rsel ? a2[1] : a2[0]) + bia[2];
    float go = (rsel ? a3[1] : a3[0]) + bia[3];
    NONLIN1(gi, gf, gg, go, 1);
    bar_lds();
  }

  // ---- switch to folded weights: W_eff = dW_hh + dW_ih@oW ; b_eff ----
  {
    const float* weff = ws;
    const float* beff = ws + 512*128;
    #pragma unroll
    for (int nt = 0; nt < 4; ++nt)
      #pragma unroll
      for (int kt = 0; kt < 4; ++kt) whh[nt*4+kt] = load_wfrag(weff, nt*128 + jown, kt*32 + q*8, Hn);
    #pragma unroll
    for (int g = 0; g < 4; ++g) bia[g] = beff[g*128 + jown];
  }

  float* outp0 = out + (size_t)(b0+0)*Tn*Dn;
  float* outp1 = out + (size_t)(b0+1)*Tn*Dn;

#define DEC_STEP(RB) do { \
    HH16(RB); \
    if (w < 4) { \
      float4v ya = mfma16(hf0, ow0, zz); \
      ya = mfma16(hf1, ow1, ya); ya = mfma16(hf2, ow2, ya); ya = mfma16(hf3, ow3, ya); \
      if (q == 0) { outp0[ocol] = ya[0] + obv; outp1[ocol] = ya[1] + obv; } \
    } \
    outp0 += Dn; outp1 += Dn; \
    float gi = (rsel ? a0[1] : a0[0]) + bia[0]; \
    float gf = (rsel ? a1[1] : a1[0]) + bia[1]; \
    float gg = (rsel ? a2[1] : a2[0]) + bia[2]; \
    float go = (rsel ? a3[1] : a3[0]) + bia[3]; \
    NONLIN1(gi, gf, gg, go, (RB)^1); \
    bar_lds(); \
  } while(0)

  // ---- decoder steps 1..511; y(i-1) computed from the same h(i) fragments ----
  #pragma unroll 1
  for (int i = 1; i < Tn-1; i += 2) {
    DEC_STEP(1);
    DEC_STEP(0);
  }
  DEC_STEP(1);

  // ---- epilogue: y(511) from h(512) (buffer 0) ----
  if (w < 4) {
    short8v hf0 = RH(0,0), hf1 = RH(0,64), hf2 = RH(0,128), hf3 = RH(0,192);
    float4v ya = {0.f,0.f,0.f,0.f};
    ya = mfma16(hf0, ow0, ya); ya = mfma16(hf1, ow1, ya);
    ya = mfma16(hf2, ow2, ya); ya = mfma16(hf3, ow3, ya);
    if (q == 0) {
      outp0[ocol] = ya[0] + obv;
      outp1[ocol] = ya[1] + obv;
    }
  }
#undef DEC_STEP
#undef ENC_STEP
#undef HH16
#undef NONLIN1
#undef BATCH
#undef RGX
#undef RH
}

extern "C" void kernel_launch(void* const* d_in, const int* in_sizes, int n_in,
                              void* d_out, int out_size, void* d_ws, size_t ws_size,
                              hipStream_t stream) {
  (void)in_sizes; (void)n_in; (void)ws_size; (void)out_size;
  const float* x     = (const float*)d_in[0];
  const float* eps   = (const float*)d_in[1];
  const float* eW_ih = (const float*)d_in[2];
  const float* eW_hh = (const float*)d_in[3];
  const float* eb_ih = (const float*)d_in[4];
  const float* eb_hh = (const float*)d_in[5];
  const float* muW   = (const float*)d_in[6];
  const float* mub   = (const float*)d_in[7];
  const float* lvW   = (const float*)d_in[8];
  const float* lvb   = (const float*)d_in[9];
  const float* iW    = (const float*)d_in[10];
  const float* ib    = (const float*)d_in[11];
  const float* dW_ih = (const float*)d_in[12];
  const float* dW_hh = (const float*)d_in[13];
  const float* db_ih = (const float*)d_in[14];
  const float* db_hh = (const float*)d_in[15];
  const float* oW    = (const float*)d_in[16];
  const float* ob    = (const float*)d_in[17];
  float* out = (float*)d_out;
  float* ws  = (float*)d_ws;

  weff_kernel<<<dim3(258), dim3(256), 0, stream>>>(dW_ih, dW_hh, db_ih, db_hh, oW, ob, ws);
  vae_fused<<<dim3(256), dim3(512), 0, stream>>>(
      x, eps, eW_ih, eW_hh, eb_ih, eb_hh, muW, mub, lvW, lvb,
      iW, ib, dW_hh, db_ih, db_hh, oW, ob, ws, out);
}

// Round 10
// 510.261 us; speedup vs baseline: 1.3657x; 1.1392x over previous
//
#include <hip/hip_runtime.h>

#define Bn 512
#define Tn 512
#define Dn 64
#define Hn 128
#define Ln 32
#define GXT   4112            // gx t-stride bytes (q-groups land on bank offsets 0/8/16/24)
#define GXBUF (8*GXT)         // bytes per gx buffer (8 timesteps)
#define HRS   320             // h row stride: row0 -> banks 0-15, row1 -> banks 16-31
#define HBUF  (2*HRS)         // bytes per h buffer

typedef __attribute__((ext_vector_type(8))) short short8v;
typedef __attribute__((ext_vector_type(4))) float float4v;
typedef __attribute__((ext_vector_type(2))) float float2v;

__device__ __forceinline__ unsigned short f2bf(float f){
  unsigned int u = __float_as_uint(f);
  u += 0x7FFFu + ((u >> 16) & 1u);           // round-to-nearest-even
  return (unsigned short)(u >> 16);
}

__device__ __forceinline__ short8v pack8(float4v a, float4v b){
  short8v r;
  r[0]=(short)f2bf(a[0]); r[1]=(short)f2bf(a[1]);
  r[2]=(short)f2bf(a[2]); r[3]=(short)f2bf(a[3]);
  r[4]=(short)f2bf(b[0]); r[5]=(short)f2bf(b[1]);
  r[6]=(short)f2bf(b[2]); r[7]=(short)f2bf(b[3]);
  return r;
}

// B-fragment for mfma_f32_16x16x32_bf16: lane holds W[n=base+(lane&15)][k0 + 8*(lane>>4) + i]
__device__ __forceinline__ short8v load_wfrag(const float* __restrict__ W, int n, int k0, int ldk){
  const float* p = W + (size_t)n*(size_t)ldk + (size_t)k0;
  float4v a = *(const float4v*)p;
  float4v b = *(const float4v*)(p+4);
  return pack8(a,b);
}

__device__ __forceinline__ float4v mfma16(short8v a, short8v b, float4v c){
  return __builtin_amdgcn_mfma_f32_16x16x32_bf16(a, b, c, 0, 0, 0);
}

__device__ __forceinline__ float sigm(float v){
  return __builtin_amdgcn_rcpf(1.0f + __expf(-v));
}
__device__ __forceinline__ float tanh_(float v){
  return 1.0f - 2.0f*__builtin_amdgcn_rcpf(1.0f + __expf(2.0f*v));
}

// Raw barrier: lgkmcnt-only drain (no vmcnt) so global loads/stores stay in flight.
__device__ __forceinline__ void bar_lds(){
  __builtin_amdgcn_sched_barrier(0);
  asm volatile("s_waitcnt lgkmcnt(0)" ::: "memory");
  __builtin_amdgcn_s_barrier();
  __builtin_amdgcn_sched_barrier(0);
}

// ---------------- precompute: W_eff = dW_hh + dW_ih @ oW ; b_eff = bd + dW_ih @ ob ----------------
__global__ __launch_bounds__(256) void weff_kernel(
    const float* __restrict__ dW_ih, const float* __restrict__ dW_hh,
    const float* __restrict__ db_ih, const float* __restrict__ db_hh,
    const float* __restrict__ oW,    const float* __restrict__ ob,
    float* __restrict__ ws)
{
  int id = blockIdx.x*256 + threadIdx.x;
  if (id < 512*128) {
    int n = id >> 7, h = id & 127;
    float s = dW_hh[id];
    #pragma unroll 8
    for (int d = 0; d < Dn; ++d) s += dW_ih[n*Dn + d] * oW[d*Hn + h];
    ws[id] = s;
  } else if (id < 512*128 + 512) {
    int n = id - 512*128;
    float s = db_ih[n] + db_hh[n];
    #pragma unroll 8
    for (int d = 0; d < Dn; ++d) s += dW_ih[n*Dn + d] * ob[d];
    ws[512*128 + n] = s;
  }
}

// ---------------- main fused kernel: 8 waves, 2 rows/block ----------------
__global__ __launch_bounds__(512, 2) void vae_fused(
    const float* __restrict__ x,     const float* __restrict__ eps,
    const float* __restrict__ eW_ih, const float* __restrict__ eW_hh,
    const float* __restrict__ eb_ih, const float* __restrict__ eb_hh,
    const float* __restrict__ muW,   const float* __restrict__ mub,
    const float* __restrict__ lvW,   const float* __restrict__ lvb,
    const float* __restrict__ iW,    const float* __restrict__ ib,
    const float* __restrict__ dW_hh, const float* __restrict__ db_ih,
    const float* __restrict__ db_hh, const float* __restrict__ oW,
    const float* __restrict__ ob,    const float* __restrict__ ws,
    float* __restrict__ out)
{
  __shared__ __align__(16) char gxb[2*GXBUF];     // ~64 KB: double-buffered gx [t][gate][col][r]
  __shared__ __align__(16) char h_lds[2*HBUF];    // 1.25 KB: double-buffered h, 2 rows @ stride 320
  __shared__ __align__(16) float sc_h[2*Hn];
  __shared__ __align__(16) float sc_mu[2*Ln];
  __shared__ __align__(16) float sc_lv[2*Ln];
  __shared__ __align__(16) float sc_z[2*Ln];

  const int tid  = threadIdx.x;
  const int lane = tid & 63;
  const int w    = tid >> 6;           // wave 0..7: owns h-indices [w*16, w*16+16)
  const int m    = lane & 15;          // fragment col (C) / A row
  const int q    = lane >> 4;          // k-group
  const int hrow = m & 1;              // replicated batch row for h/A reads
  const int rsel = q & 1;              // batch row this lane's nonlin chain owns
  const int jown = w*16 + m;           // h-index this lane owns
  const int b0   = blockIdx.x * 2;
  // per-lane LDS pointers (new conflict-free layout)
  char* const hw_p  = h_lds + q*HRS + 2*jown;          // h write (valid q<2; q==rsel there)
  const char* const hr_p = h_lds + hrow*HRS + q*16;    // h-frag read base
  const char* const rgx_p = gxb + jown*8 + rsel*4;     // gx read base (b32, only needed r)
  char* const gwx_p = gxb + jown*8 + q*(2*GXT);        // gx write base (t=2q)

  // ---- zero h buffers ----
  if (tid < (2*HBUF)/4) ((int*)h_lds)[tid] = 0;

  // ---- encoder weights: tile nt (=gate) -> row n = nt*128 + jown ----
  short8v wih[8];    // [nt*2+kt] : 4H x D
  short8v whh[16];   // [nt*4+kt] : 4H x H
  #pragma unroll
  for (int nt = 0; nt < 4; ++nt) {
    #pragma unroll
    for (int kt = 0; kt < 2; ++kt) wih[nt*2+kt] = load_wfrag(eW_ih, nt*128 + jown, kt*32 + q*8, Dn);
    #pragma unroll
    for (int kt = 0; kt < 4; ++kt) whh[nt*4+kt] = load_wfrag(eW_hh, nt*128 + jown, kt*32 + q*8, Hn);
  }
  float bia[4];
  #pragma unroll
  for (int g = 0; g < 4; ++g) bia[g] = eb_ih[g*128 + jown] + eb_hh[g*128 + jown];

  // ---- x batch registers: lane (m,q) holds x[b0+(m&1)][tb*8 + (m>>1)][q*8 ..+8, +32..] ----
  const float* xptr = x + (size_t)(b0 + hrow)*Tn*Dn + (size_t)(m>>1)*Dn + q*8;
  float4v xc0,xc1,xc2,xc3, xn0,xn1,xn2,xn3;
  xc0 = *(const float4v*)(xptr+0);  xc1 = *(const float4v*)(xptr+4);
  xc2 = *(const float4v*)(xptr+32); xc3 = *(const float4v*)(xptr+36);
  xptr += 512;                       // now points at tb=1
  int xnext = 1;                     // next tb to load

  float cst = 0.f, hval = 0.f;       // per-lane c/h for (rsel, jown)
  __syncthreads();

#define RH(RB,KB)    (*(const short8v*)(hr_p + (RB)*HBUF + (KB)))
#define RGX(CB,S,NT) (*(const float*)(rgx_p + (CB)*GXBUF + (S)*GXT + (NT)*1024))

  // gx batch for the NEXT 8-step window into buffer PB. No barrier of its own:
  // >=8 bar_lds separate these stores from their first read.
  // C row q*4+j -> (t = 2q+(j>>1), r = j&1).
#define BATCH(PB) do { \
    short8v xf0 = pack8(xc0, xc1); \
    short8v xf1 = pack8(xc2, xc3); \
    if (xnext < 64) { \
      xn0 = *(const float4v*)(xptr+0);  xn1 = *(const float4v*)(xptr+4); \
      xn2 = *(const float4v*)(xptr+32); xn3 = *(const float4v*)(xptr+36); \
      xptr += 512; \
    } \
    ++xnext; \
    float4v zz = {0.f,0.f,0.f,0.f}; \
    float4v c0_ = mfma16(xf0, wih[0], zz); \
    float4v c1_ = mfma16(xf0, wih[2], zz); \
    float4v c2_ = mfma16(xf0, wih[4], zz); \
    float4v c3_ = mfma16(xf0, wih[6], zz); \
    c0_ = mfma16(xf1, wih[1], c0_); \
    c1_ = mfma16(xf1, wih[3], c1_); \
    c2_ = mfma16(xf1, wih[5], c2_); \
    c3_ = mfma16(xf1, wih[7], c3_); \
    char* gp = gwx_p + (PB)*GXBUF; \
    *(float2v*)(gp +       0) = (float2v){c0_[0]+bia[0], c0_[1]+bia[0]}; \
    *(float2v*)(gp +    1024) = (float2v){c1_[0]+bia[1], c1_[1]+bia[1]}; \
    *(float2v*)(gp +    2048) = (float2v){c2_[0]+bia[2], c2_[1]+bia[2]}; \
    *(float2v*)(gp +    3072) = (float2v){c3_[0]+bia[3], c3_[1]+bia[3]}; \
    *(float2v*)(gp + GXT +    0) = (float2v){c0_[2]+bia[0], c0_[3]+bia[0]}; \
    *(float2v*)(gp + GXT + 1024) = (float2v){c1_[2]+bia[1], c1_[3]+bia[1]}; \
    *(float2v*)(gp + GXT + 2048) = (float2v){c2_[2]+bia[2], c2_[3]+bia[2]}; \
    *(float2v*)(gp + GXT + 3072) = (float2v){c3_[2]+bia[3], c3_[3]+bia[3]}; \
    xc0=xn0; xc1=xn1; xc2=xn2; xc3=xn3; \
  } while(0)

  // ONE chain per lane (r = q&1); q=0/1 lanes write rows 0/1, q=2/3 redundant SIMT copies.
#define NONLIN1(GI,GF,GG,GO, WB) do { \
    float c = sigm(GF)*cst + sigm(GI)*tanh_(GG); \
    cst = c; \
    hval = sigm(GO)*tanh_(c); \
    if (q < 2) *(unsigned short*)(hw_p + (WB)*HBUF) = f2bf(hval); \
  } while(0)

#define HH16(RB) \
    short8v hf0 = RH(RB,0), hf1 = RH(RB,64), hf2 = RH(RB,128), hf3 = RH(RB,192); \
    float4v zz = {0.f,0.f,0.f,0.f}; \
    float4v a0 = mfma16(hf0, whh[0],  zz); \
    float4v a1 = mfma16(hf0, whh[4],  zz); \
    float4v a2 = mfma16(hf0, whh[8],  zz); \
    float4v a3 = mfma16(hf0, whh[12], zz); \
    a0 = mfma16(hf1, whh[1],  a0); a1 = mfma16(hf1, whh[5],  a1); \
    a2 = mfma16(hf1, whh[9],  a2); a3 = mfma16(hf1, whh[13], a3); \
    a0 = mfma16(hf2, whh[2],  a0); a1 = mfma16(hf2, whh[6],  a1); \
    a2 = mfma16(hf2, whh[10], a2); a3 = mfma16(hf2, whh[14], a3); \
    a0 = mfma16(hf3, whh[3],  a0); a1 = mfma16(hf3, whh[7],  a1); \
    a2 = mfma16(hf3, whh[11], a2); a3 = mfma16(hf3, whh[15], a3);

  // step S (of the 8-step window): read buffer RB = S&1, gx buffer CB. PRODUCE: issue
  // BATCH into the other gx buffer AFTER nonlin (fills MFMA pipe during VALU phase).
#define ENC_STEP(S, CB) do { \
    float g0 = RGX(CB,S,0), g1 = RGX(CB,S,1), g2 = RGX(CB,S,2), g3 = RGX(CB,S,3); \
    HH16((S)&1); \
    float gi = (rsel ? a0[1] : a0[0]) + g0; \
    float gf = (rsel ? a1[1] : a1[0]) + g1; \
    float gg = (rsel ? a2[1] : a2[0]) + g2; \
    float go = (rsel ? a3[1] : a3[0]) + g3; \
    NONLIN1(gi, gf, gg, go, ((S)&1)^1); \
    bar_lds(); \
  } while(0)

#define ENC_STEP0(CB, PRODUCE) do { \
    float g0 = RGX(CB,0,0), g1 = RGX(CB,0,1), g2 = RGX(CB,0,2), g3 = RGX(CB,0,3); \
    HH16(0); \
    float gi = (rsel ? a0[1] : a0[0]) + g0; \
    float gf = (rsel ? a1[1] : a1[0]) + g1; \
    float gg = (rsel ? a2[1] : a2[0]) + g2; \
    float go = (rsel ? a3[1] : a3[0]) + g3; \
    NONLIN1(gi, gf, gg, go, 1); \
    if (PRODUCE) BATCH((CB)^1); \
    bar_lds(); \
  } while(0)

#define ENC8(CB, PRODUCE) do { \
    ENC_STEP0(CB, PRODUCE); \
    ENC_STEP(1,CB); ENC_STEP(2,CB); ENC_STEP(3,CB); \
    ENC_STEP(4,CB); ENC_STEP(5,CB); ENC_STEP(6,CB); ENC_STEP(7,CB); \
  } while(0)

  // ================= encoder: 64 batches x 8 steps =================
  BATCH(0);            // gx(tb=0) -> buf0; loads x(tb=1)
  bar_lds();
  #pragma unroll 1
  for (int tb2 = 0; tb2 < 32; ++tb2) {
    ENC8(0, 1);                  // consume buf0, produce buf1 (tb=2*tb2+1)
    ENC8(1, (tb2 < 31));         // consume buf1, produce buf0 (tb=2*tb2+2), skip last
  }
  // final h in buffer 0; exact f32 copy of owned element in hval (lanes q<2)

  // ================= latent =================
  if (q < 2) sc_h[rsel*Hn + jown] = hval;
  __syncthreads();

  if (tid < 128) {
    const int isLv = tid >> 6;
    const int rr   = (tid >> 5) & 1;
    const int l    = tid & 31;
    const float* Wp = isLv ? lvW : muW;
    float s = isLv ? lvb[l] : mub[l];
    #pragma unroll
    for (int k = 0; k < Hn; k += 4) {
      float4v wv = *(const float4v*)(Wp + l*Hn + k);
      float4v hv = *(const float4v*)(sc_h + rr*Hn + k);
      s += wv[0]*hv[0] + wv[1]*hv[1] + wv[2]*hv[2] + wv[3]*hv[3];
    }
    out[(size_t)Bn*Tn*Dn + (size_t)isLv*Bn*Ln + (size_t)(b0+rr)*Ln + l] = s;
    (isLv ? sc_lv : sc_mu)[rr*Ln + l] = s;
  }
  __syncthreads();

  if (tid < 64) {
    int rr = tid >> 5, l = tid & 31;
    sc_z[rr*Ln+l] = sc_mu[rr*Ln+l] + eps[(size_t)(b0+rr)*Ln + l] * __expf(0.5f * sc_lv[rr*Ln+l]);
  }
  __syncthreads();

  if (tid < 256) { // decoder hidden init -> h buffer 0
    int rr = tid >> 7, jj = tid & 127;
    float s = ib[jj];
    #pragma unroll
    for (int l = 0; l < Ln; ++l) s += sc_z[rr*Ln + l] * iW[jj*Ln + l];
    *(unsigned short*)(h_lds + rr*HRS + 2*jj) = f2bf(s);
  }
  cst = 0.f;

  // ---- decoder step-0 weights (dW_hh, bd) + output-proj fragments ----
  #pragma unroll
  for (int nt = 0; nt < 4; ++nt)
    #pragma unroll
    for (int kt = 0; kt < 4; ++kt) whh[nt*4+kt] = load_wfrag(dW_hh, nt*128 + jown, kt*32 + q*8, Hn);
  #pragma unroll
  for (int g = 0; g < 4; ++g) bia[g] = db_ih[g*128 + jown] + db_hh[g*128 + jown];
  const int ocol = (w & 3)*16 + m;
  short8v ow0 = load_wfrag(oW, ocol,  0 + q*8, Hn);
  short8v ow1 = load_wfrag(oW, ocol, 32 + q*8, Hn);
  short8v ow2 = load_wfrag(oW, ocol, 64 + q*8, Hn);
  short8v ow3 = load_wfrag(oW, ocol, 96 + q*8, Hn);
  const float obv = ob[ocol];
  __syncthreads();

  // ---- decoder step 0: gates = h0 @ dW_hh^T + bd (input is zero) ----
  {
    HH16(0);
    float gi = (rsel ? a0[1] : a0[0]) + bia[0];
    float gf = (rsel ? a1[1] : a1[0]) + bia[1];
    float gg = (rsel ? a2[1] : a2[0]) + bia[2];
    float go = (rsel ? a3[1] : a3[0]) + bia[3];
    NONLIN1(gi, gf, gg, go, 1);
    bar_lds();
  }

  // ---- switch to folded weights: W_eff = dW_hh + dW_ih@oW ; b_eff ----
  {
    const float* weff = ws;
    const float* beff = ws + 512*128;
    #pragma unroll
    for (int nt = 0; nt < 4; ++nt)
      #pragma unroll
      for (int kt = 0; kt < 4; ++kt) whh[nt*4+kt] = load_wfrag(weff, nt*128 + jown, kt*32 + q*8, Hn);
    #pragma unroll
    for (int g = 0; g < 4; ++g) bia[g] = beff[g*128 + jown];
  }

  float* outp0 = out + (size_t)(b0+0)*Tn*Dn;
  float* outp1 = out + (size_t)(b0+1)*Tn*Dn;

  // nonlin FIRST (critical path), y-proj MFMAs after (fills pipe while other waves nonlin)
#define DEC_STEP(RB) do { \
    HH16(RB); \
    float gi = (rsel ? a0[1] : a0[0]) + bia[0]; \
    float gf = (rsel ? a1[1] : a1[0]) + bia[1]; \
    float gg = (rsel ? a2[1] : a2[0]) + bia[2]; \
    float go = (rsel ? a3[1] : a3[0]) + bia[3]; \
    NONLIN1(gi, gf, gg, go, (RB)^1); \
    if (w < 4) { \
      float4v ya = mfma16(hf0, ow0, zz); \
      ya = mfma16(hf1, ow1, ya); ya = mfma16(hf2, ow2, ya); ya = mfma16(hf3, ow3, ya); \
      if (q == 0) { outp0[ocol] = ya[0] + obv; outp1[ocol] = ya[1] + obv; } \
    } \
    outp0 += Dn; outp1 += Dn; \
    bar_lds(); \
  } while(0)

  // ---- decoder steps 1..511; y(i-1) computed from the same h(i) fragments ----
  #pragma unroll 1
  for (int i = 1; i < Tn-1; i += 2) {
    DEC_STEP(1);
    DEC_STEP(0);
  }
  DEC_STEP(1);

  // ---- epilogue: y(511) from h(512) (buffer 0) ----
  if (w < 4) {
    short8v hf0 = RH(0,0), hf1 = RH(0,64), hf2 = RH(0,128), hf3 = RH(0,192);
    float4v ya = {0.f,0.f,0.f,0.f};
    ya = mfma16(hf0, ow0, ya); ya = mfma16(hf1, ow1, ya);
    ya = mfma16(hf2, ow2, ya); ya = mfma16(hf3, ow3, ya);
    if (q == 0) {
      outp0[ocol] = ya[0] + obv;
      outp1[ocol] = ya[1] + obv;
    }
  }
#undef DEC_STEP
#undef ENC8
#undef ENC_STEP0
#undef ENC_STEP
#undef HH16
#undef NONLIN1
#undef BATCH
#undef RGX
#undef RH
}

extern "C" void kernel_launch(void* const* d_in, const int* in_sizes, int n_in,
                              void* d_out, int out_size, void* d_ws, size_t ws_size,
                              hipStream_t stream) {
  (void)in_sizes; (void)n_in; (void)ws_size; (void)out_size;
  const float* x     = (const float*)d_in[0];
  const float* eps   = (const float*)d_in[1];
  const float* eW_ih = (const float*)d_in[2];
  const float* eW_hh = (const float*)d_in[3];
  const float* eb_ih = (const float*)d_in[4];
  const float* eb_hh = (const float*)d_in[5];
  const float* muW   = (const float*)d_in[6];
  const float* mub   = (const float*)d_in[7];
  const float* lvW   = (const float*)d_in[8];
  const float* lvb   = (const float*)d_in[9];
  const float* iW    = (const float*)d_in[10];
  const float* ib    = (const float*)d_in[11];
  const float* dW_ih = (const float*)d_in[12];
  const float* dW_hh = (const float*)d_in[13];
  const float* db_ih = (const float*)d_in[14];
  const float* db_hh = (const float*)d_in[15];
  const float* oW    = (const float*)d_in[16];
  const float* ob    = (const float*)d_in[17];
  float* out = (float*)d_out;
  float* ws  = (float*)d_ws;

  weff_kernel<<<dim3(258), dim3(256), 0, stream>>>(dW_ih, dW_hh, db_ih, db_hh, oW, ob, ws);
  vae_fused<<<dim3(256), dim3(512), 0, stream>>>(
      x, eps, eW_ih, eW_hh, eb_ih, eb_hh, muW, mub, lvW, lvb,
      iW, ib, dW_hh, db_ih, db_hh, oW, ob, ws, out);
}